// Round 14
// baseline (274.212 us; speedup 1.0000x reference)
//
#include <hip/hip_runtime.h>
#include <cmath>

using u16 = unsigned short;
using u32 = unsigned int;
using bf16x8 = __attribute__((ext_vector_type(8))) __bf16;
using f32x4  = __attribute__((ext_vector_type(4))) float;

__device__ inline u16 f2bf(float f) {
  u32 u = __float_as_uint(f);
  u32 r = (u + 0x7fffu + ((u >> 16) & 1u)) >> 16;  // RNE
  return (u16)r;
}
__device__ inline float bf2f(u16 v) { return __uint_as_float(((u32)v) << 16); }

// ---- prep1 (256-thr): LN | w0 transpose | wq/wk/wv bf16 cast | u,v,wb | sb --
__global__ __launch_bounds__(256) void prep1(
    const float* __restrict__ x, const float* __restrict__ lnw,
    const float* __restrict__ lnb, const float* __restrict__ wq,
    const float* __restrict__ wk, const float* __restrict__ wv,
    const float* __restrict__ w0, const float* __restrict__ bq,
    const float* __restrict__ bk, const float* __restrict__ bv,
    u16* __restrict__ xn, u16* __restrict__ w0t, u16* __restrict__ wqb,
    u16* __restrict__ wkb, u16* __restrict__ wvb, float* __restrict__ uvec,
    float* __restrict__ vvec, float* __restrict__ wb, float* __restrict__ sb) {
  int b = blockIdx.x;
  int tid = threadIdx.x;
  __shared__ float red[4];
  __shared__ float red2[4];
  int lane = tid & 63, wave = tid >> 6;
  if (b < 16384) {  // LayerNorm
    const float4* xr = (const float4*)(x + (size_t)b * 1024);
    float4 v = xr[tid];
    float s  = v.x + v.y + v.z + v.w;
    float ss = v.x * v.x + v.y * v.y + v.z * v.z + v.w * v.w;
#pragma unroll
    for (int o = 32; o >= 1; o >>= 1) {
      s  += __shfl_xor(s, o, 64);
      ss += __shfl_xor(ss, o, 64);
    }
    if (lane == 0) { red[wave] = s; red2[wave] = ss; }
    __syncthreads();
    s  = red[0] + red[1] + red[2] + red[3];
    ss = red2[0] + red2[1] + red2[2] + red2[3];
    float mean = s * (1.0f / 1024.0f);
    float var  = ss * (1.0f / 1024.0f) - mean * mean;
    float rstd = rsqrtf(var + 1e-5f);
    int c = tid * 4;
    ushort4 ov;
    ov.x = f2bf((v.x - mean) * rstd * lnw[c + 0] + lnb[c + 0]);
    ov.y = f2bf((v.y - mean) * rstd * lnw[c + 1] + lnb[c + 1]);
    ov.z = f2bf((v.z - mean) * rstd * lnw[c + 2] + lnb[c + 2]);
    ov.w = f2bf((v.w - mean) * rstd * lnw[c + 3] + lnb[c + 3]);
    ((ushort4*)(xn + (size_t)b * 1024))[tid] = ov;
  } else if (b < 17408) {  // transpose w0 -> w0t
    int b2 = b - 16384;
    int c0 = (b2 & 31) * 32, r0 = (b2 >> 5) * 32;
    int tx = tid & 31, ty = tid >> 5;
    __shared__ float tile[32][33];
#pragma unroll
    for (int i = 0; i < 32; i += 8)
      tile[ty + i][tx] = w0[(size_t)(r0 + ty + i) * 1024 + c0 + tx];
    __syncthreads();
#pragma unroll
    for (int i = 0; i < 32; i += 8)
      w0t[(size_t)(c0 + ty + i) * 1024 + r0 + tx] = f2bf(tile[tx][ty + i]);
  } else if (b < 18944) {  // cast wq/wk/wv -> bf16 row-major
    int b3 = b - 17408;
    int mat = b3 / 512, blk = b3 % 512;
    const float* src = (mat == 0) ? wq : (mat == 1) ? wk : wv;
    u16* dst = (mat == 0) ? wqb : (mat == 1) ? wkb : wvb;
    size_t base = (size_t)blk * 2048 + (size_t)tid * 8;
#pragma unroll
    for (int i = 0; i < 8; ++i) dst[base + i] = f2bf(src[base + i]);
  } else if (b < 22016) {  // u[c], v[c], wb[e]
    int b4 = b - 18944;
    int which = b4 >> 10, idx = b4 & 1023;
    float p = 0.f;
    if (which == 0) {  // u[c] = sum_e wq[c][e] bk[e]
      const float* r = wq + (size_t)idx * 1024;
      for (int e = tid * 4; e < (tid + 1) * 4; ++e) p += r[e] * bk[e];
    } else if (which == 1) {  // v[c] = sum_e wk[c][e] bq[e]
      const float* r = wk + (size_t)idx * 1024;
      for (int e = tid * 4; e < (tid + 1) * 4; ++e) p += r[e] * bq[e];
    } else {  // wb[e] = sum_d bv[d] w0[d][e]
      for (int d = tid * 4; d < (tid + 1) * 4; ++d)
        p += bv[d] * w0[(size_t)d * 1024 + idx];
    }
#pragma unroll
    for (int o = 32; o >= 1; o >>= 1) p += __shfl_xor(p, o, 64);
    if (lane == 0) red[wave] = p;
    __syncthreads();
    if (tid == 0) {
      float t = red[0] + red[1] + red[2] + red[3];
      if (which == 0) uvec[idx] = t;
      else if (which == 1) vvec[idx] = t;
      else wb[idx] = t;
    }
  } else {  // sb = bq . bk
    float p = 0.f;
    for (int e = tid * 4; e < (tid + 1) * 4; ++e) p += bq[e] * bk[e];
#pragma unroll
    for (int o = 32; o >= 1; o >>= 1) p += __shfl_xor(p, o, 64);
    if (lane == 0) red[wave] = p;
    __syncthreads();
    if (tid == 0) sb[0] = red[0] + red[1] + red[2] + red[3];
  }
}

// ============== R3-VERBATIM 256x256 8-phase bf16 GEMM (measured 118.7 us) ====
// Used ONLY for the xnG projection (rule #19: do not touch this source form).
template <int OUTF32, int MODE>
__global__ __launch_bounds__(512, 2) void gemm256(
    const u16* __restrict__ A, const u16* __restrict__ B, void* __restrict__ Cv,
    const float* __restrict__ bias, int K, int lda, int ldb, int ldc,
    float scale, long long sA, long long sB, long long sC) {
  int gx = gridDim.x;
  int wg = blockIdx.y * gx + blockIdx.x;
  {
    int nwg = gx * gridDim.y;
    if ((nwg & 7) == 0) {
      int q = nwg >> 3;
      wg = (wg & 7) * q + (wg >> 3);
    }
  }
  const int ti = wg / gx, tj = wg % gx, bz = blockIdx.z;
  if (MODE == 1 && tj < ti) return;

  const u16* Ab = A + (size_t)bz * (size_t)sA;
  const u16* Bb = B + (size_t)bz * (size_t)sB;

  __shared__ u16 As[2][256 * 64];
  __shared__ u16 Bs[2][256 * 64];

  const int tid = threadIdx.x;
  const int wave = tid >> 6, lane = tid & 63;
  const int wr = wave >> 2, wc = wave & 3;
  const int fr = lane & 15;
  const int kb16 = (lane >> 4) * 16;
  const int swz = (fr & 7) << 4;
  const int cs0 = kb16 ^ swz;
  const int cs1 = (64 + kb16) ^ swz;
  const int aRowOff = (wr * 128 + fr) * 128;
  const int bRowOff = (wc * 64 + fr) * 128;

  size_t gAo[2][2], gBo[2][2];
  u32 ldsA[2][2], ldsB[2][2];
#pragma unroll
  for (int h = 0; h < 2; ++h) {
#pragma unroll
    for (int l = 0; l < 2; ++l) {
      int i = l * 512 + tid;
      int rih = i >> 3, ch8 = i & 7;
      int rA = (rih & 63) + ((rih >> 6) << 7) + h * 64;
      int cbA = (ch8 << 4) ^ ((rA & 7) << 4);
      gAo[h][l] = (size_t)rA * lda + (cbA >> 1);
      ldsA[h][l] = (u32)(rA * 8 + ch8) * 16;
      int rB = (rih & 31) + ((rih >> 5) << 6) + h * 32;
      int cbB = (ch8 << 4) ^ ((rB & 7) << 4);
      gBo[h][l] = (size_t)rB * ldb + (cbB >> 1);
      ldsB[h][l] = (u32)(rB * 8 + ch8) * 16;
    }
  }
  const size_t aBase = (size_t)(ti * 256) * lda;
  const size_t bBase = (size_t)(tj * 256) * ldb;

  const int k0 = (MODE == 2) ? ti * 256 : 0;
  const int niter = (K - k0) / 128;

  f32x4 acc[8][4] = {};
  bf16x8 aF[4][2], bF[4][2];

#define GLL(gaddr, laddr)                                        \
  __builtin_amdgcn_global_load_lds(                              \
      (const __attribute__((address_space(1))) void*)(gaddr),    \
      (__attribute__((address_space(3))) void*)(laddr), 16, 0, 0)

#define STAGE_A(buf, h, t)                                                     \
  do {                                                                         \
    const size_t _kt = aBase + (size_t)(k0 + (t) * 64);                        \
    GLL(Ab + _kt + gAo[h][0], (char*)&As[buf][0] + ldsA[h][0]);                \
    GLL(Ab + _kt + gAo[h][1], (char*)&As[buf][0] + ldsA[h][1]);                \
  } while (0)
#define STAGE_B(buf, h, t)                                                     \
  do {                                                                         \
    const size_t _kt = bBase + (size_t)(k0 + (t) * 64);                        \
    GLL(Bb + _kt + gBo[h][0], (char*)&Bs[buf][0] + ldsB[h][0]);                \
    GLL(Bb + _kt + gBo[h][1], (char*)&Bs[buf][0] + ldsB[h][1]);                \
  } while (0)

#define DS_A(buf, qm)                                                \
  do {                                                               \
    const char* _pa = (const char*)&As[buf][0] + aRowOff + (qm)*8192;\
    _Pragma("unroll") for (int mm = 0; mm < 4; ++mm) {               \
      aF[mm][0] = *(const bf16x8*)(_pa + mm * 2048 + cs0);           \
      aF[mm][1] = *(const bf16x8*)(_pa + mm * 2048 + cs1);           \
    }                                                                \
  } while (0)
#define DS_B(buf, nh)                                                \
  do {                                                               \
    const char* _pb = (const char*)&Bs[buf][0] + bRowOff;            \
    _Pragma("unroll") for (int nn = 0; nn < 2; ++nn) {               \
      bF[(nh)*2 + nn][0] = *(const bf16x8*)(_pb + ((nh)*2 + nn) * 2048 + cs0); \
      bF[(nh)*2 + nn][1] = *(const bf16x8*)(_pb + ((nh)*2 + nn) * 2048 + cs1); \
    }                                                                \
  } while (0)

#define MMA(qm, nh)                                                          \
  do {                                                                       \
    _Pragma("unroll") for (int mm = 0; mm < 4; ++mm)                         \
    _Pragma("unroll") for (int nn = 0; nn < 2; ++nn) {                       \
      f32x4 _c = acc[(qm)*4 + mm][(nh)*2 + nn];                              \
      _c = __builtin_amdgcn_mfma_f32_16x16x32_bf16(aF[mm][0], bF[(nh)*2+nn][0], _c, 0, 0, 0); \
      _c = __builtin_amdgcn_mfma_f32_16x16x32_bf16(aF[mm][1], bF[(nh)*2+nn][1], _c, 0, 0, 0); \
      acc[(qm)*4 + mm][(nh)*2 + nn] = _c;                                    \
    }                                                                        \
  } while (0)

#define BAR __builtin_amdgcn_s_barrier()
#define LGKM0 asm volatile("s_waitcnt lgkmcnt(0)" ::: "memory")
#define VM6 asm volatile("s_waitcnt vmcnt(6)" ::: "memory")
#define VM0 asm volatile("s_waitcnt vmcnt(0)" ::: "memory")
#define PRIO1 __builtin_amdgcn_s_setprio(1)
#define PRIO0 __builtin_amdgcn_s_setprio(0)

  STAGE_B(0, 0, 0); STAGE_B(0, 1, 0); STAGE_A(0, 0, 0); STAGE_A(0, 1, 0);
  STAGE_B(1, 0, 1); STAGE_B(1, 1, 1); STAGE_A(1, 0, 1);
  VM6; BAR;

  for (int it = 0; it < niter; ++it) {
    const bool last = (it == niter - 1);
    const int t1g = 2 * it + 1, t2g = 2 * it + 2, t3g = 2 * it + 3;

    DS_A(0, 0); DS_B(0, 0);
    STAGE_A(1, 1, t1g);
    BAR; LGKM0; PRIO1; MMA(0, 0); PRIO0; BAR;
    DS_B(0, 1);
    if (!last) STAGE_B(0, 0, t2g);
    BAR; LGKM0; PRIO1; MMA(0, 1); PRIO0; BAR;
    DS_A(0, 1);
    if (!last) STAGE_B(0, 1, t2g);
    BAR; LGKM0; PRIO1; MMA(1, 0); PRIO0; BAR;
    if (!last) STAGE_A(0, 0, t2g);
    BAR; PRIO1; MMA(1, 1); PRIO0;
    if (last) { VM0; } else { VM6; }
    BAR;
    DS_A(1, 0); DS_B(1, 0);
    if (!last) STAGE_A(0, 1, t2g);
    BAR; LGKM0; PRIO1; MMA(0, 0); PRIO0; BAR;
    DS_B(1, 1);
    if (!last) STAGE_B(1, 0, t3g);
    BAR; LGKM0; PRIO1; MMA(0, 1); PRIO0; BAR;
    DS_A(1, 1);
    if (!last) STAGE_B(1, 1, t3g);
    BAR; LGKM0; PRIO1; MMA(1, 0); PRIO0; BAR;
    if (!last) STAGE_A(1, 0, t3g);
    BAR; PRIO1; MMA(1, 1); PRIO0;
    if (!last) VM6;
    BAR;
  }

  const int orow0 = ti * 256 + wr * 128 + ((lane >> 4) << 2);
  const int ocol0 = tj * 256 + wc * 64 + fr;
#pragma unroll
  for (int m = 0; m < 8; ++m) {
#pragma unroll
    for (int n = 0; n < 4; ++n) {
      const int col = ocol0 + n * 16;
      const float bv = bias ? bias[col] : 0.0f;
#pragma unroll
      for (int j = 0; j < 4; ++j) {
        const int row = orow0 + m * 16 + j;
        const float v = acc[m][n][j] * scale + bv;
        const size_t idx = (size_t)bz * (size_t)sC + (size_t)row * ldc + col;
        if (OUTF32) ((float*)Cv)[idx] = v;
        else        ((u16*)Cv)[idx]   = f2bf(v);
      }
    }
  }
#undef GLL
#undef STAGE_A
#undef STAGE_B
#undef DS_A
#undef DS_B
#undef MMA
#undef BAR
#undef LGKM0
#undef VM6
#undef VM0
#undef PRIO1
#undef PRIO0
}

// ============== PV clone of the verbatim kernel: loop untouched, epilogue ====
// replaced with inv-normalize (+b0, f32 out). MODE=2 k0 path used as-is.
template <int OUTF32, int MODE>
__global__ __launch_bounds__(512, 2) void gemm256_pv(
    const u16* __restrict__ A, const u16* __restrict__ B, void* __restrict__ Cv,
    const float* __restrict__ bias, int K, int lda, int ldb, int ldc,
    float scale, long long sA, long long sB, long long sC,
    const float* __restrict__ sumP) {
  int gx = gridDim.x;
  int wg = blockIdx.y * gx + blockIdx.x;
  {
    int nwg = gx * gridDim.y;
    if ((nwg & 7) == 0) {
      int q = nwg >> 3;
      wg = (wg & 7) * q + (wg >> 3);
    }
  }
  const int ti = wg / gx, tj = wg % gx, bz = blockIdx.z;
  if (MODE == 1 && tj < ti) return;

  const u16* Ab = A + (size_t)bz * (size_t)sA;
  const u16* Bb = B + (size_t)bz * (size_t)sB;

  __shared__ u16 As[2][256 * 64];
  __shared__ u16 Bs[2][256 * 64];
  __shared__ float invLds[256];

  const int tid = threadIdx.x;
  const int wave = tid >> 6, lane = tid & 63;
  const int wr = wave >> 2, wc = wave & 3;
  const int fr = lane & 15;
  const int kb16 = (lane >> 4) * 16;
  const int swz = (fr & 7) << 4;
  const int cs0 = kb16 ^ swz;
  const int cs1 = (64 + kb16) ^ swz;
  const int aRowOff = (wr * 128 + fr) * 128;
  const int bRowOff = (wc * 64 + fr) * 128;

  size_t gAo[2][2], gBo[2][2];
  u32 ldsA[2][2], ldsB[2][2];
#pragma unroll
  for (int h = 0; h < 2; ++h) {
#pragma unroll
    for (int l = 0; l < 2; ++l) {
      int i = l * 512 + tid;
      int rih = i >> 3, ch8 = i & 7;
      int rA = (rih & 63) + ((rih >> 6) << 7) + h * 64;
      int cbA = (ch8 << 4) ^ ((rA & 7) << 4);
      gAo[h][l] = (size_t)rA * lda + (cbA >> 1);
      ldsA[h][l] = (u32)(rA * 8 + ch8) * 16;
      int rB = (rih & 31) + ((rih >> 5) << 6) + h * 32;
      int cbB = (ch8 << 4) ^ ((rB & 7) << 4);
      gBo[h][l] = (size_t)rB * ldb + (cbB >> 1);
      ldsB[h][l] = (u32)(rB * 8 + ch8) * 16;
    }
  }
  const size_t aBase = (size_t)(ti * 256) * lda;
  const size_t bBase = (size_t)(tj * 256) * ldb;

  const int k0 = (MODE == 2) ? ti * 256 : 0;
  const int niter = (K - k0) / 128;

  f32x4 acc[8][4] = {};
  bf16x8 aF[4][2], bF[4][2];

#define GLL(gaddr, laddr)                                        \
  __builtin_amdgcn_global_load_lds(                              \
      (const __attribute__((address_space(1))) void*)(gaddr),    \
      (__attribute__((address_space(3))) void*)(laddr), 16, 0, 0)

#define STAGE_A(buf, h, t)                                                     \
  do {                                                                         \
    const size_t _kt = aBase + (size_t)(k0 + (t) * 64);                        \
    GLL(Ab + _kt + gAo[h][0], (char*)&As[buf][0] + ldsA[h][0]);                \
    GLL(Ab + _kt + gAo[h][1], (char*)&As[buf][0] + ldsA[h][1]);                \
  } while (0)
#define STAGE_B(buf, h, t)                                                     \
  do {                                                                         \
    const size_t _kt = bBase + (size_t)(k0 + (t) * 64);                        \
    GLL(Bb + _kt + gBo[h][0], (char*)&Bs[buf][0] + ldsB[h][0]);                \
    GLL(Bb + _kt + gBo[h][1], (char*)&Bs[buf][0] + ldsB[h][1]);                \
  } while (0)

#define DS_A(buf, qm)                                                \
  do {                                                               \
    const char* _pa = (const char*)&As[buf][0] + aRowOff + (qm)*8192;\
    _Pragma("unroll") for (int mm = 0; mm < 4; ++mm) {               \
      aF[mm][0] = *(const bf16x8*)(_pa + mm * 2048 + cs0);           \
      aF[mm][1] = *(const bf16x8*)(_pa + mm * 2048 + cs1);           \
    }                                                                \
  } while (0)
#define DS_B(buf, nh)                                                \
  do {                                                               \
    const char* _pb = (const char*)&Bs[buf][0] + bRowOff;            \
    _Pragma("unroll") for (int nn = 0; nn < 2; ++nn) {               \
      bF[(nh)*2 + nn][0] = *(const bf16x8*)(_pb + ((nh)*2 + nn) * 2048 + cs0); \
      bF[(nh)*2 + nn][1] = *(const bf16x8*)(_pb + ((nh)*2 + nn) * 2048 + cs1); \
    }                                                                \
  } while (0)

#define MMA(qm, nh)                                                          \
  do {                                                                       \
    _Pragma("unroll") for (int mm = 0; mm < 4; ++mm)                         \
    _Pragma("unroll") for (int nn = 0; nn < 2; ++nn) {                       \
      f32x4 _c = acc[(qm)*4 + mm][(nh)*2 + nn];                              \
      _c = __builtin_amdgcn_mfma_f32_16x16x32_bf16(aF[mm][0], bF[(nh)*2+nn][0], _c, 0, 0, 0); \
      _c = __builtin_amdgcn_mfma_f32_16x16x32_bf16(aF[mm][1], bF[(nh)*2+nn][1], _c, 0, 0, 0); \
      acc[(qm)*4 + mm][(nh)*2 + nn] = _c;                                    \
    }                                                                        \
  } while (0)

#define BAR __builtin_amdgcn_s_barrier()
#define LGKM0 asm volatile("s_waitcnt lgkmcnt(0)" ::: "memory")
#define VM6 asm volatile("s_waitcnt vmcnt(6)" ::: "memory")
#define VM0 asm volatile("s_waitcnt vmcnt(0)" ::: "memory")
#define PRIO1 __builtin_amdgcn_s_setprio(1)
#define PRIO0 __builtin_amdgcn_s_setprio(0)

  STAGE_B(0, 0, 0); STAGE_B(0, 1, 0); STAGE_A(0, 0, 0); STAGE_A(0, 1, 0);
  STAGE_B(1, 0, 1); STAGE_B(1, 1, 1); STAGE_A(1, 0, 1);
  VM6; BAR;

  for (int it = 0; it < niter; ++it) {
    const bool last = (it == niter - 1);
    const int t1g = 2 * it + 1, t2g = 2 * it + 2, t3g = 2 * it + 3;

    DS_A(0, 0); DS_B(0, 0);
    STAGE_A(1, 1, t1g);
    BAR; LGKM0; PRIO1; MMA(0, 0); PRIO0; BAR;
    DS_B(0, 1);
    if (!last) STAGE_B(0, 0, t2g);
    BAR; LGKM0; PRIO1; MMA(0, 1); PRIO0; BAR;
    DS_A(0, 1);
    if (!last) STAGE_B(0, 1, t2g);
    BAR; LGKM0; PRIO1; MMA(1, 0); PRIO0; BAR;
    if (!last) STAGE_A(0, 0, t2g);
    BAR; PRIO1; MMA(1, 1); PRIO0;
    if (last) { VM0; } else { VM6; }
    BAR;
    DS_A(1, 0); DS_B(1, 0);
    if (!last) STAGE_A(0, 1, t2g);
    BAR; LGKM0; PRIO1; MMA(0, 0); PRIO0; BAR;
    DS_B(1, 1);
    if (!last) STAGE_B(1, 0, t3g);
    BAR; LGKM0; PRIO1; MMA(0, 1); PRIO0; BAR;
    DS_A(1, 1);
    if (!last) STAGE_B(1, 1, t3g);
    BAR; LGKM0; PRIO1; MMA(1, 0); PRIO0; BAR;
    if (!last) STAGE_A(1, 0, t3g);
    BAR; PRIO1; MMA(1, 1); PRIO0;
    if (!last) VM6;
    BAR;
  }

  // EPI-PV: inv from sumP partials, then v = acc*inv + bias (f32 out).
  if (tid < 256) {
    int s = ti * 256 + tid;
    float a = 0.f;
    for (int q2 = s >> 8; q2 < 8; ++q2)
      a += sumP[(size_t)bz * 8 * 2048 + q2 * 2048 + s];
    invLds[tid] = 1.0f / a;
  }
  __syncthreads();

  const int orowL = wr * 128 + ((lane >> 4) << 2);
  const int orow0 = ti * 256 + orowL;
  const int ocol0 = tj * 256 + wc * 64 + fr;
#pragma unroll
  for (int m = 0; m < 8; ++m) {
#pragma unroll
    for (int n = 0; n < 4; ++n) {
      const int col = ocol0 + n * 16;
      const float bv = bias ? bias[col] : 0.0f;
#pragma unroll
      for (int j = 0; j < 4; ++j) {
        const int row = orow0 + m * 16 + j;
        const float v = acc[m][n][j] * invLds[orowL + m * 16 + j] + bv;
        const size_t idx = (size_t)bz * (size_t)sC + (size_t)row * ldc + col;
        ((float*)Cv)[idx] = v;
      }
    }
  }
#undef GLL
#undef STAGE_A
#undef STAGE_B
#undef DS_A
#undef DS_B
#undef MMA
#undef BAR
#undef LGKM0
#undef VM6
#undef VM0
#undef PRIO1
#undef PRIO0
}

// ---------------- BMx256 8-phase body (Gt/Uw/Wt/QK paths) -------------------
// EPI 0: bf16 out (+col-bias +row-bias). EPI 1: QK — E=exp(clamp((acc+ru+rv)
// *scale)-5), mask cl<rl+dco, bf16 store + row partial sums -> sumP.
template <int BM, int EPI, int LDA, int LDB, int LDC, int KK, int K0CT>
__device__ __forceinline__ void gemm_body(
    const u16* __restrict__ Ab, const u16* __restrict__ Bb,
    void* __restrict__ Cp, const float* __restrict__ bias,
    const float* __restrict__ rbias, int rk0, float scale, size_t cbase,
    int ti, int tj, u16* __restrict__ AsP, u16* __restrict__ BsP,
    float* __restrict__ sumP, int dco,
    const float* __restrict__ ruP, const float* __restrict__ rvP) {
  constexpr int WM = BM / 2;
  constexpr int MH = BM / 64;
  constexpr int FM = 2 * MH;
  constexpr int HR = BM / 4;
  constexpr int LA = BM / 128;

  const int k0 = (K0CT >= 0) ? K0CT : rk0;

  const int tid = threadIdx.x;
  const int wave = tid >> 6, lane = tid & 63;
  const int wr = wave >> 2, wc = wave & 3;
  const int fr = lane & 15;
  const int kb16 = (lane >> 4) * 16;
  const int swz = (fr & 7) << 4;
  const int cs0 = kb16 ^ swz;
  const int cs1 = (64 + kb16) ^ swz;
  const int aRowOff = (wr * WM + fr) * 128;
  const int bRowOff = (wc * 64 + fr) * 128;

  size_t gAo[2][LA], gBo[2][2];
  u32 ldsA[2][LA], ldsB[2][2];
#pragma unroll
  for (int h = 0; h < 2; ++h) {
#pragma unroll
    for (int l = 0; l < LA; ++l) {
      int i = l * 512 + tid;
      int rih = i >> 3, ch8 = i & 7;
      int rA = (rih % HR) + (rih / HR) * WM + h * HR;
      int cbA = (ch8 << 4) ^ ((rA & 7) << 4);
      gAo[h][l] = (size_t)rA * LDA + (cbA >> 1);
      ldsA[h][l] = (u32)(rA * 8 + ch8) * 16;
    }
#pragma unroll
    for (int l = 0; l < 2; ++l) {
      int i = l * 512 + tid;
      int rih = i >> 3, ch8 = i & 7;
      int rB = (rih & 31) + ((rih >> 5) << 6) + h * 32;
      int cbB = (ch8 << 4) ^ ((rB & 7) << 4);
      gBo[h][l] = (size_t)rB * LDB + (cbB >> 1);
      ldsB[h][l] = (u32)(rB * 8 + ch8) * 16;
    }
  }
  const size_t aBase = (size_t)(ti * BM) * LDA;
  const size_t bBase = (size_t)(tj * 256) * LDB;
  const int niter = (KK - k0) / 128;

  f32x4 acc[FM][4] = {};
  bf16x8 aF[MH][2], bF[4][2];

#define GLL(gaddr, laddr)                                        \
  __builtin_amdgcn_global_load_lds(                              \
      (const __attribute__((address_space(1))) void*)(gaddr),    \
      (__attribute__((address_space(3))) void*)(laddr), 16, 0, 0)

#define STAGE_A(buf, h, t)                                                   \
  do {                                                                       \
    const size_t _kt = aBase + (size_t)(k0 + (t) * 64);                      \
    _Pragma("unroll") for (int _l = 0; _l < LA; ++_l)                        \
        GLL(Ab + _kt + gAo[h][_l],                                           \
            (char*)(AsP + (buf) * (BM * 64)) + ldsA[h][_l]);                 \
  } while (0)
#define STAGE_B(buf, h, t)                                                   \
  do {                                                                       \
    const size_t _kt = bBase + (size_t)(k0 + (t) * 64);                      \
    _Pragma("unroll") for (int _l = 0; _l < 2; ++_l)                         \
        GLL(Bb + _kt + gBo[h][_l],                                           \
            (char*)(BsP + (buf) * (256 * 64)) + ldsB[h][_l]);                \
  } while (0)

#define DS_A(buf, qm)                                                        \
  do {                                                                       \
    const char* _pa =                                                        \
        (const char*)(AsP + (buf) * (BM * 64)) + aRowOff + (qm) * (MH * 2048); \
    _Pragma("unroll") for (int mm = 0; mm < MH; ++mm) {                      \
      aF[mm][0] = *(const bf16x8*)(_pa + mm * 2048 + cs0);                   \
      aF[mm][1] = *(const bf16x8*)(_pa + mm * 2048 + cs1);                   \
    }                                                                        \
  } while (0)
#define DS_B(buf, nh)                                                        \
  do {                                                                       \
    const char* _pb = (const char*)(BsP + (buf) * (256 * 64)) + bRowOff;     \
    _Pragma("unroll") for (int nn = 0; nn < 2; ++nn) {                       \
      bF[(nh)*2 + nn][0] = *(const bf16x8*)(_pb + ((nh)*2 + nn) * 2048 + cs0); \
      bF[(nh)*2 + nn][1] = *(const bf16x8*)(_pb + ((nh)*2 + nn) * 2048 + cs1); \
    }                                                                        \
  } while (0)

#define MMA(qm, nh)                                                          \
  do {                                                                       \
    _Pragma("unroll") for (int mm = 0; mm < MH; ++mm)                        \
    _Pragma("unroll") for (int nn = 0; nn < 2; ++nn) {                       \
      f32x4 _c = acc[(qm)*MH + mm][(nh)*2 + nn];                             \
      _c = __builtin_amdgcn_mfma_f32_16x16x32_bf16(aF[mm][0], bF[(nh)*2+nn][0], _c, 0, 0, 0); \
      _c = __builtin_amdgcn_mfma_f32_16x16x32_bf16(aF[mm][1], bF[(nh)*2+nn][1], _c, 0, 0, 0); \
      acc[(qm)*MH + mm][(nh)*2 + nn] = _c;                                   \
    }                                                                        \
  } while (0)

#define BAR __builtin_amdgcn_s_barrier()
#define LGKM0 asm volatile("s_waitcnt lgkmcnt(0)" ::: "memory")
#define VMN                                                                  \
  do {                                                                       \
    if constexpr (BM == 256)                                                 \
      asm volatile("s_waitcnt vmcnt(6)" ::: "memory");                       \
    else                                                                     \
      asm volatile("s_waitcnt vmcnt(5)" ::: "memory");                       \
  } while (0)
#define VM0 asm volatile("s_waitcnt vmcnt(0)" ::: "memory")
#define PRIO1 __builtin_amdgcn_s_setprio(1)
#define PRIO0 __builtin_amdgcn_s_setprio(0)

  STAGE_B(0, 0, 0); STAGE_B(0, 1, 0); STAGE_A(0, 0, 0); STAGE_A(0, 1, 0);
  STAGE_B(1, 0, 1); STAGE_B(1, 1, 1); STAGE_A(1, 0, 1);
  VMN; BAR;

#pragma unroll 1
  for (int it = 0; it < niter; ++it) {
    const bool last = (it == niter - 1);
    const int t1g = 2 * it + 1, t2g = 2 * it + 2, t3g = 2 * it + 3;

    DS_A(0, 0); DS_B(0, 0);
    STAGE_A(1, 1, t1g);
    BAR; LGKM0; PRIO1; MMA(0, 0); PRIO0; BAR;
    DS_B(0, 1);
    if (!last) STAGE_B(0, 0, t2g);
    BAR; LGKM0; PRIO1; MMA(0, 1); PRIO0; BAR;
    DS_A(0, 1);
    if (!last) STAGE_B(0, 1, t2g);
    BAR; LGKM0; PRIO1; MMA(1, 0); PRIO0; BAR;
    if (!last) STAGE_A(0, 0, t2g);
    BAR; PRIO1; MMA(1, 1); PRIO0;
    if (last) { VM0; } else { VMN; }
    BAR;
    DS_A(1, 0); DS_B(1, 0);
    if (!last) STAGE_A(0, 1, t2g);
    BAR; LGKM0; PRIO1; MMA(0, 0); PRIO0; BAR;
    DS_B(1, 1);
    if (!last) STAGE_B(1, 0, t3g);
    BAR; LGKM0; PRIO1; MMA(0, 1); PRIO0; BAR;
    DS_A(1, 1);
    if (!last) STAGE_B(1, 1, t3g);
    BAR; LGKM0; PRIO1; MMA(1, 0); PRIO0; BAR;
    if (!last) STAGE_A(1, 0, t3g);
    BAR; PRIO1; MMA(1, 1); PRIO0;
    if (!last) VMN;
    BAR;
  }

  const int orowL = wr * WM + ((lane >> 4) << 2);
  const int orow0 = ti * BM + orowL;
  const int ocol0 = tj * 256 + wc * 64 + fr;

  if constexpr (EPI == 1) {
    float* slds = (float*)AsP;  // [BM][4] cross-wave reduce buffer
#pragma unroll
    for (int m = 0; m < FM; ++m) {
#pragma unroll
      for (int j = 0; j < 4; ++j) {
        const int rl = orowL + m * 16 + j;
        const int row = ti * BM + rl;
        const float ru = ruP[row];
        float rsum = 0.f;
#pragma unroll
        for (int n = 0; n < 4; ++n) {
          const int cl = wc * 64 + fr + n * 16;
          const int col = tj * 256 + cl;
          float v = (acc[m][n][j] + ru + rvP[col]) * scale;
          v = fminf(fmaxf(v, -1.0e9f), 1.0e9f);  // CLAMP
          v = fminf(v, 60.0f);                   // overflow guard
          float e = __expf(v - 5.0f);
          if (cl < rl + dco) e = 0.f;            // causal-complement mask
          rsum += e;
          ((u16*)Cp)[cbase + (size_t)row * LDC + col] = f2bf(e);
        }
        rsum += __shfl_xor(rsum, 1, 64);
        rsum += __shfl_xor(rsum, 2, 64);
        rsum += __shfl_xor(rsum, 4, 64);
        rsum += __shfl_xor(rsum, 8, 64);
        if (fr == 0) slds[rl * 4 + wc] = rsum;
      }
    }
    __syncthreads();
    if (tid < BM) {
      float t = slds[tid * 4 + 0] + slds[tid * 4 + 1] +
                slds[tid * 4 + 2] + slds[tid * 4 + 3];
      sumP[ti * BM + tid] = t;
    }
  } else {
#pragma unroll
    for (int m = 0; m < FM; ++m) {
#pragma unroll
      for (int j = 0; j < 4; ++j) {
        const int row = orow0 + m * 16 + j;
        float rb = rbias ? rbias[row] : 0.0f;
#pragma unroll
        for (int n = 0; n < 4; ++n) {
          const int col = ocol0 + n * 16;
          const float bv = bias ? bias[col] : 0.0f;
          const size_t idx = cbase + (size_t)row * LDC + col;
          ((u16*)Cp)[idx] = f2bf(acc[m][n][j] + bv + rb);
        }
      }
    }
  }
#undef GLL
#undef STAGE_A
#undef STAGE_B
#undef DS_A
#undef DS_B
#undef MMA
#undef BAR
#undef LGKM0
#undef VMN
#undef VM0
#undef PRIO1
#undef PRIO0
}

// ---- prep2 (512-thr): Gt (32 blk) | Uw (32 blk) | ruv filler (512 blk) -----
__global__ __launch_bounds__(512, 2) void prep2(
    const u16* __restrict__ wqb, const u16* __restrict__ wkb,
    const u16* __restrict__ wvb, const u16* __restrict__ w0t,
    const u16* __restrict__ xn, const float* __restrict__ uvec,
    const float* __restrict__ vvec, const float* __restrict__ sb,
    u16* __restrict__ Gt, u16* __restrict__ Uw,
    float* __restrict__ ru, float* __restrict__ rv) {
  __shared__ u16 As[2][128 * 64];
  __shared__ u16 Bs[2][256 * 64];
  int b = blockIdx.x;
  if (b < 32) {
    // Gt[c][d] = sum_e wk[c][e] wq[d][e]
    int ti = b & 7, tj = b >> 3;
    gemm_body<128, 0, 1024, 1024, 1024, 1024, 0>(
        wkb, wqb, Gt, nullptr, nullptr, 0, 1.0f, 0, ti, tj,
        &As[0][0], &Bs[0][0], nullptr, 0, nullptr, nullptr);
  } else if (b < 64) {
    // Uw[e][c] = sum_d w0t[e][d] wv[c][d]
    int b2 = b - 32;
    int ti = b2 & 7, tj = b2 >> 3;
    gemm_body<128, 0, 1024, 1024, 1024, 1024, 0>(
        w0t, wvb, Uw, nullptr, nullptr, 0, 1.0f, 0, ti, tj,
        &As[0][0], &Bs[0][0], nullptr, 0, nullptr, nullptr);
  } else {
    // ruv: 32 rows/block, 4 rows/wave
    int b2 = b - 64;  // 0..511
    int wv = threadIdx.x >> 6, lane = threadIdx.x & 63;
    int rbase = b2 * 32 + wv * 4;
#pragma unroll
    for (int rr = 0; rr < 4; ++rr) {
      int r = rbase + rr;
      const u16* row = xn + (size_t)r * 1024;
      int c0 = lane * 16;
      float pu = 0.f, pv = 0.f;
#pragma unroll
      for (int i = 0; i < 16; ++i) {
        float xv = bf2f(row[c0 + i]);
        pu += xv * uvec[c0 + i];
        pv += xv * vvec[c0 + i];
      }
#pragma unroll
      for (int o = 32; o >= 1; o >>= 1) {
        pu += __shfl_xor(pu, o, 64);
        pv += __shfl_xor(pv, o, 64);
      }
      if (lane == 0) { ru[r] = pu + sb[0]; rv[r] = pv; }
    }
  }
}

// ---- combined QK^T (BM=256, first, LPT) + Wt (BM=128, filler) --------------
__global__ __launch_bounds__(512, 2) void gemm_qkwt(
    const u16* __restrict__ xnG, const u16* __restrict__ xn,
    const u16* __restrict__ Uw, u16* __restrict__ Wt, u16* __restrict__ sc,
    float* __restrict__ sumP, const float* __restrict__ ru,
    const float* __restrict__ rv, const float* __restrict__ wb,
    int qkBlocks, int b0, int nb, float qk_scale) {
  __shared__ u16 As[2][256 * 64];
  __shared__ u16 Bs[2][256 * 64];
  const long long sXN = 2048LL * 1024, sWt = 1024LL * 2048, sS = 2048LL * 2048;
  int x = blockIdx.x;
  if (x < qkBlocks) {
    int bzl = x % nb, t36 = x / nb;
    int bz = b0 + bzl;
    int tq = 0, rem = t36;
    for (;;) { int L = 8 - tq; if (rem < L) break; rem -= L; ++tq; }
    int tj = tq + rem;
    gemm_body<256, 1, 1024, 1024, 2048, 1024, 0>(
        xnG + (size_t)bz * sXN, xn + (size_t)bz * sXN, sc, nullptr, nullptr,
        0, qk_scale, (size_t)bzl * sS, tq, tj, &As[0][0], &Bs[0][0],
        sumP + ((size_t)bz * 8 + tj) * 2048, (tq - tj) * 256,
        ru + (size_t)bz * 2048, rv + (size_t)bz * 2048);
  } else {
    int x2 = x - qkBlocks;           // 0..511
    int bz = x2 & 7;                 // XCD affinity
    int o = x2 >> 3;                 // 0..63
    int ti = o & 7, tj = o >> 3;     // ti-fastest
    gemm_body<128, 0, 1024, 1024, 2048, 1024, 0>(
        Uw, xn + (size_t)bz * sXN, Wt, nullptr, wb, 0, 1.0f,
        (size_t)bz * sWt, ti, tj, &As[0][0], &Bs[0][0],
        nullptr, 0, nullptr, nullptr);
  }
}

extern "C" void kernel_launch(void* const* d_in, const int* in_sizes, int n_in,
                              void* d_out, int out_size, void* d_ws, size_t ws_size,
                              hipStream_t stream) {
  (void)in_sizes; (void)n_in; (void)out_size;
  const float* x   = (const float*)d_in[0];
  const float* lnw = (const float*)d_in[1];
  const float* lnb = (const float*)d_in[2];
  const float* wq  = (const float*)d_in[3];
  const float* bq  = (const float*)d_in[4];
  const float* wk  = (const float*)d_in[5];
  const float* bk  = (const float*)d_in[6];
  const float* wv  = (const float*)d_in[7];
  const float* bv  = (const float*)d_in[8];
  const float* w0  = (const float*)d_in[9];
  const float* b0  = (const float*)d_in[10];
  float* out = (float*)d_out;

  const size_t ROWS = 16384;  // B*S
  char* ws = (char*)d_ws;
  size_t off = 0;
  auto alloc = [&](size_t bytes) -> void* {
    void* p = ws + off;
    off += (bytes + 255) & ~(size_t)255;
    return p;
  };
  u16*   xn   = (u16*)alloc(ROWS * 1024 * 2);            // 32 MB
  u16*   w0t  = (u16*)alloc((size_t)1024 * 1024 * 2);    // 2 MB
  u16*   wqb  = (u16*)alloc((size_t)1024 * 1024 * 2);
  u16*   wkb  = (u16*)alloc((size_t)1024 * 1024 * 2);
  u16*   wvb  = (u16*)alloc((size_t)1024 * 1024 * 2);
  u16*   Gt   = (u16*)alloc((size_t)1024 * 1024 * 2);
  u16*   Uw   = (u16*)alloc((size_t)1024 * 1024 * 2);
  float* uvec = (float*)alloc(1024 * 4);
  float* vvec = (float*)alloc(1024 * 4);
  float* wb   = (float*)alloc(1024 * 4);
  float* sb   = (float*)alloc(256);
  float* ru   = (float*)alloc(ROWS * 4);                 // 64 KB
  float* rv   = (float*)alloc(ROWS * 4);
  float* sumP = (float*)alloc((size_t)8 * 8 * 2048 * 4); // 512 KB
  u16*   xnG  = (u16*)alloc(ROWS * 1024 * 2);            // 32 MB
  u16*   Wt   = (u16*)alloc(ROWS * 1024 * 2);            // 32 MB [8][1024][2048]

  const size_t CHUNK1 = (size_t)2048 * 2048 * 2;  // 8 MB per batch (E bf16)
  size_t avail = (ws_size > off) ? ws_size - off : 0;
  int NBCH = (int)(avail / CHUNK1);
  if (NBCH > 8) NBCH = 8;
  if (NBCH < 1) NBCH = 1;
  u16* sc = (u16*)(ws + off);

  // D1: LN + w0 transpose + weight casts + u/v/wb/sb
  prep1<<<dim3(22017), dim3(256), 0, stream>>>(
      x, lnw, lnb, wq, wk, wv, w0, bq, bk, bv,
      xn, w0t, wqb, wkb, wvb, uvec, vvec, wb, sb);
  // D2: Gt, Uw (weight-space GEMMs) + ru/rv filler
  prep2<<<dim3(576), dim3(512), 0, stream>>>(
      wqb, wkb, wvb, w0t, xn, uvec, vvec, sb, Gt, Uw, ru, rv);
  // D3: xnG = xn @ G  (verbatim fast kernel; 256 blocks = 1 round)
  gemm256<0, 0><<<dim3(4, 64, 1), dim3(512), 0, stream>>>(
      xn, Gt, xnG, nullptr, 1024, 1024, 1024, 1024, 1.0f, 0, 0, 0);

  float qk_scale = (float)(1.0 / (std::sqrt(1024.0) + 1e-9));

  for (int bA = 0; bA < 8; bA += NBCH) {
    int nb = 8 - bA;
    if (nb > NBCH) nb = NBCH;
    int qkB = nb * 36;
    int wtB = (bA == 0) ? 512 : 0;  // Wt (BM=128) for ALL batches, first pass
    gemm_qkwt<<<dim3(qkB + wtB), dim3(512), 0, stream>>>(
        xnG, xn, Uw, Wt, sc, sumP, ru, rv, wb, qkB, bA, nb, qk_scale);
    // PV via verbatim-clone (BM=256, MODE=2 k0 path, LPT ti-ascending)
    gemm256_pv<1, 2><<<dim3(4, 8, nb), dim3(512), 0, stream>>>(
        sc, Wt + (size_t)bA * 1024 * 2048, (void*)(out + (size_t)bA * 2048 * 1024),
        b0, 2048, 2048, 2048, 1024, 1.0f,
        2048LL * 2048, 1024LL * 2048, 2048LL * 1024,
        sumP + (size_t)bA * 8 * 2048);
  }
}

// Round 15
// 264.711 us; speedup vs baseline: 1.0359x; 1.0359x over previous
//
#include <hip/hip_runtime.h>
#include <cmath>

using u16 = unsigned short;
using u32 = unsigned int;
using bf16x8 = __attribute__((ext_vector_type(8))) __bf16;
using f32x4  = __attribute__((ext_vector_type(4))) float;

__device__ inline u16 f2bf(float f) {
  u32 u = __float_as_uint(f);
  u32 r = (u + 0x7fffu + ((u >> 16) & 1u)) >> 16;  // RNE
  return (u16)r;
}
__device__ inline float bf2f(u16 v) { return __uint_as_float(((u32)v) << 16); }

// ---- prep1 (256-thr): LN | w0 transpose | wq/wk/wv bf16 cast | u,v,wb | sb --
__global__ __launch_bounds__(256) void prep1(
    const float* __restrict__ x, const float* __restrict__ lnw,
    const float* __restrict__ lnb, const float* __restrict__ wq,
    const float* __restrict__ wk, const float* __restrict__ wv,
    const float* __restrict__ w0, const float* __restrict__ bq,
    const float* __restrict__ bk, const float* __restrict__ bv,
    u16* __restrict__ xn, u16* __restrict__ w0t, u16* __restrict__ wqb,
    u16* __restrict__ wkb, u16* __restrict__ wvb, float* __restrict__ uvec,
    float* __restrict__ vvec, float* __restrict__ wb, float* __restrict__ sb) {
  int b = blockIdx.x;
  int tid = threadIdx.x;
  __shared__ float red[4];
  __shared__ float red2[4];
  int lane = tid & 63, wave = tid >> 6;
  if (b < 16384) {  // LayerNorm
    const float4* xr = (const float4*)(x + (size_t)b * 1024);
    float4 v = xr[tid];
    float s  = v.x + v.y + v.z + v.w;
    float ss = v.x * v.x + v.y * v.y + v.z * v.z + v.w * v.w;
#pragma unroll
    for (int o = 32; o >= 1; o >>= 1) {
      s  += __shfl_xor(s, o, 64);
      ss += __shfl_xor(ss, o, 64);
    }
    if (lane == 0) { red[wave] = s; red2[wave] = ss; }
    __syncthreads();
    s  = red[0] + red[1] + red[2] + red[3];
    ss = red2[0] + red2[1] + red2[2] + red2[3];
    float mean = s * (1.0f / 1024.0f);
    float var  = ss * (1.0f / 1024.0f) - mean * mean;
    float rstd = rsqrtf(var + 1e-5f);
    int c = tid * 4;
    ushort4 ov;
    ov.x = f2bf((v.x - mean) * rstd * lnw[c + 0] + lnb[c + 0]);
    ov.y = f2bf((v.y - mean) * rstd * lnw[c + 1] + lnb[c + 1]);
    ov.z = f2bf((v.z - mean) * rstd * lnw[c + 2] + lnb[c + 2]);
    ov.w = f2bf((v.w - mean) * rstd * lnw[c + 3] + lnb[c + 3]);
    ((ushort4*)(xn + (size_t)b * 1024))[tid] = ov;
  } else if (b < 17408) {  // transpose w0 -> w0t
    int b2 = b - 16384;
    int c0 = (b2 & 31) * 32, r0 = (b2 >> 5) * 32;
    int tx = tid & 31, ty = tid >> 5;
    __shared__ float tile[32][33];
#pragma unroll
    for (int i = 0; i < 32; i += 8)
      tile[ty + i][tx] = w0[(size_t)(r0 + ty + i) * 1024 + c0 + tx];
    __syncthreads();
#pragma unroll
    for (int i = 0; i < 32; i += 8)
      w0t[(size_t)(c0 + ty + i) * 1024 + r0 + tx] = f2bf(tile[tx][ty + i]);
  } else if (b < 18944) {  // cast wq/wk/wv -> bf16 row-major
    int b3 = b - 17408;
    int mat = b3 / 512, blk = b3 % 512;
    const float* src = (mat == 0) ? wq : (mat == 1) ? wk : wv;
    u16* dst = (mat == 0) ? wqb : (mat == 1) ? wkb : wvb;
    size_t base = (size_t)blk * 2048 + (size_t)tid * 8;
#pragma unroll
    for (int i = 0; i < 8; ++i) dst[base + i] = f2bf(src[base + i]);
  } else if (b < 22016) {  // u[c], v[c], wb[e]
    int b4 = b - 18944;
    int which = b4 >> 10, idx = b4 & 1023;
    float p = 0.f;
    if (which == 0) {  // u[c] = sum_e wq[c][e] bk[e]
      const float* r = wq + (size_t)idx * 1024;
      for (int e = tid * 4; e < (tid + 1) * 4; ++e) p += r[e] * bk[e];
    } else if (which == 1) {  // v[c] = sum_e wk[c][e] bq[e]
      const float* r = wk + (size_t)idx * 1024;
      for (int e = tid * 4; e < (tid + 1) * 4; ++e) p += r[e] * bq[e];
    } else {  // wb[e] = sum_d bv[d] w0[d][e]
      for (int d = tid * 4; d < (tid + 1) * 4; ++d)
        p += bv[d] * w0[(size_t)d * 1024 + idx];
    }
#pragma unroll
    for (int o = 32; o >= 1; o >>= 1) p += __shfl_xor(p, o, 64);
    if (lane == 0) red[wave] = p;
    __syncthreads();
    if (tid == 0) {
      float t = red[0] + red[1] + red[2] + red[3];
      if (which == 0) uvec[idx] = t;
      else if (which == 1) vvec[idx] = t;
      else wb[idx] = t;
    }
  } else {  // sb = bq . bk
    float p = 0.f;
    for (int e = tid * 4; e < (tid + 1) * 4; ++e) p += bq[e] * bk[e];
#pragma unroll
    for (int o = 32; o >= 1; o >>= 1) p += __shfl_xor(p, o, 64);
    if (lane == 0) red[wave] = p;
    __syncthreads();
    if (tid == 0) sb[0] = red[0] + red[1] + red[2] + red[3];
  }
}

// ---- ruv: per row r, ru[r]=xn[r].u+sb, rv[r]=xn[r].v (8 rows/block) --------
__global__ __launch_bounds__(512) void ruv_kernel(
    const u16* __restrict__ xn, const float* __restrict__ uvec,
    const float* __restrict__ vvec, const float* __restrict__ sb,
    float* __restrict__ ru, float* __restrict__ rv) {
  int wv = threadIdx.x >> 6, lane = threadIdx.x & 63;
  int r = blockIdx.x * 8 + wv;
  const u16* row = xn + (size_t)r * 1024;
  int c0 = lane * 16;
  float pu = 0.f, pv = 0.f;
#pragma unroll
  for (int i = 0; i < 16; ++i) {
    float xv = bf2f(row[c0 + i]);
    pu += xv * uvec[c0 + i];
    pv += xv * vvec[c0 + i];
  }
#pragma unroll
  for (int o = 32; o >= 1; o >>= 1) {
    pu += __shfl_xor(pu, o, 64);
    pv += __shfl_xor(pv, o, 64);
  }
  if (lane == 0) { ru[r] = pu + sb[0]; rv[r] = pv; }
}

// ============== R3-VERBATIM 256x256 8-phase bf16 GEMM (measured 118.7 us) ====
// Used ONLY for the xnG projection (rule #19: do not touch this source form).
template <int OUTF32, int MODE>
__global__ __launch_bounds__(512, 2) void gemm256(
    const u16* __restrict__ A, const u16* __restrict__ B, void* __restrict__ Cv,
    const float* __restrict__ bias, int K, int lda, int ldb, int ldc,
    float scale, long long sA, long long sB, long long sC) {
  int gx = gridDim.x;
  int wg = blockIdx.y * gx + blockIdx.x;
  {
    int nwg = gx * gridDim.y;
    if ((nwg & 7) == 0) {
      int q = nwg >> 3;
      wg = (wg & 7) * q + (wg >> 3);
    }
  }
  const int ti = wg / gx, tj = wg % gx, bz = blockIdx.z;
  if (MODE == 1 && tj < ti) return;

  const u16* Ab = A + (size_t)bz * (size_t)sA;
  const u16* Bb = B + (size_t)bz * (size_t)sB;

  __shared__ u16 As[2][256 * 64];
  __shared__ u16 Bs[2][256 * 64];

  const int tid = threadIdx.x;
  const int wave = tid >> 6, lane = tid & 63;
  const int wr = wave >> 2, wc = wave & 3;
  const int fr = lane & 15;
  const int kb16 = (lane >> 4) * 16;
  const int swz = (fr & 7) << 4;
  const int cs0 = kb16 ^ swz;
  const int cs1 = (64 + kb16) ^ swz;
  const int aRowOff = (wr * 128 + fr) * 128;
  const int bRowOff = (wc * 64 + fr) * 128;

  size_t gAo[2][2], gBo[2][2];
  u32 ldsA[2][2], ldsB[2][2];
#pragma unroll
  for (int h = 0; h < 2; ++h) {
#pragma unroll
    for (int l = 0; l < 2; ++l) {
      int i = l * 512 + tid;
      int rih = i >> 3, ch8 = i & 7;
      int rA = (rih & 63) + ((rih >> 6) << 7) + h * 64;
      int cbA = (ch8 << 4) ^ ((rA & 7) << 4);
      gAo[h][l] = (size_t)rA * lda + (cbA >> 1);
      ldsA[h][l] = (u32)(rA * 8 + ch8) * 16;
      int rB = (rih & 31) + ((rih >> 5) << 6) + h * 32;
      int cbB = (ch8 << 4) ^ ((rB & 7) << 4);
      gBo[h][l] = (size_t)rB * ldb + (cbB >> 1);
      ldsB[h][l] = (u32)(rB * 8 + ch8) * 16;
    }
  }
  const size_t aBase = (size_t)(ti * 256) * lda;
  const size_t bBase = (size_t)(tj * 256) * ldb;

  const int k0 = (MODE == 2) ? ti * 256 : 0;
  const int niter = (K - k0) / 128;

  f32x4 acc[8][4] = {};
  bf16x8 aF[4][2], bF[4][2];

#define GLL(gaddr, laddr)                                        \
  __builtin_amdgcn_global_load_lds(                              \
      (const __attribute__((address_space(1))) void*)(gaddr),    \
      (__attribute__((address_space(3))) void*)(laddr), 16, 0, 0)

#define STAGE_A(buf, h, t)                                                     \
  do {                                                                         \
    const size_t _kt = aBase + (size_t)(k0 + (t) * 64);                        \
    GLL(Ab + _kt + gAo[h][0], (char*)&As[buf][0] + ldsA[h][0]);                \
    GLL(Ab + _kt + gAo[h][1], (char*)&As[buf][0] + ldsA[h][1]);                \
  } while (0)
#define STAGE_B(buf, h, t)                                                     \
  do {                                                                         \
    const size_t _kt = bBase + (size_t)(k0 + (t) * 64);                        \
    GLL(Bb + _kt + gBo[h][0], (char*)&Bs[buf][0] + ldsB[h][0]);                \
    GLL(Bb + _kt + gBo[h][1], (char*)&Bs[buf][0] + ldsB[h][1]);                \
  } while (0)

#define DS_A(buf, qm)                                                \
  do {                                                               \
    const char* _pa = (const char*)&As[buf][0] + aRowOff + (qm)*8192;\
    _Pragma("unroll") for (int mm = 0; mm < 4; ++mm) {               \
      aF[mm][0] = *(const bf16x8*)(_pa + mm * 2048 + cs0);           \
      aF[mm][1] = *(const bf16x8*)(_pa + mm * 2048 + cs1);           \
    }                                                                \
  } while (0)
#define DS_B(buf, nh)                                                \
  do {                                                               \
    const char* _pb = (const char*)&Bs[buf][0] + bRowOff;            \
    _Pragma("unroll") for (int nn = 0; nn < 2; ++nn) {               \
      bF[(nh)*2 + nn][0] = *(const bf16x8*)(_pb + ((nh)*2 + nn) * 2048 + cs0); \
      bF[(nh)*2 + nn][1] = *(const bf16x8*)(_pb + ((nh)*2 + nn) * 2048 + cs1); \
    }                                                                \
  } while (0)

#define MMA(qm, nh)                                                          \
  do {                                                                       \
    _Pragma("unroll") for (int mm = 0; mm < 4; ++mm)                         \
    _Pragma("unroll") for (int nn = 0; nn < 2; ++nn) {                       \
      f32x4 _c = acc[(qm)*4 + mm][(nh)*2 + nn];                              \
      _c = __builtin_amdgcn_mfma_f32_16x16x32_bf16(aF[mm][0], bF[(nh)*2+nn][0], _c, 0, 0, 0); \
      _c = __builtin_amdgcn_mfma_f32_16x16x32_bf16(aF[mm][1], bF[(nh)*2+nn][1], _c, 0, 0, 0); \
      acc[(qm)*4 + mm][(nh)*2 + nn] = _c;                                    \
    }                                                                        \
  } while (0)

#define BAR __builtin_amdgcn_s_barrier()
#define LGKM0 asm volatile("s_waitcnt lgkmcnt(0)" ::: "memory")
#define VM6 asm volatile("s_waitcnt vmcnt(6)" ::: "memory")
#define VM0 asm volatile("s_waitcnt vmcnt(0)" ::: "memory")
#define PRIO1 __builtin_amdgcn_s_setprio(1)
#define PRIO0 __builtin_amdgcn_s_setprio(0)

  STAGE_B(0, 0, 0); STAGE_B(0, 1, 0); STAGE_A(0, 0, 0); STAGE_A(0, 1, 0);
  STAGE_B(1, 0, 1); STAGE_B(1, 1, 1); STAGE_A(1, 0, 1);
  VM6; BAR;

  for (int it = 0; it < niter; ++it) {
    const bool last = (it == niter - 1);
    const int t1g = 2 * it + 1, t2g = 2 * it + 2, t3g = 2 * it + 3;

    DS_A(0, 0); DS_B(0, 0);
    STAGE_A(1, 1, t1g);
    BAR; LGKM0; PRIO1; MMA(0, 0); PRIO0; BAR;
    DS_B(0, 1);
    if (!last) STAGE_B(0, 0, t2g);
    BAR; LGKM0; PRIO1; MMA(0, 1); PRIO0; BAR;
    DS_A(0, 1);
    if (!last) STAGE_B(0, 1, t2g);
    BAR; LGKM0; PRIO1; MMA(1, 0); PRIO0; BAR;
    if (!last) STAGE_A(0, 0, t2g);
    BAR; PRIO1; MMA(1, 1); PRIO0;
    if (last) { VM0; } else { VM6; }
    BAR;
    DS_A(1, 0); DS_B(1, 0);
    if (!last) STAGE_A(0, 1, t2g);
    BAR; LGKM0; PRIO1; MMA(0, 0); PRIO0; BAR;
    DS_B(1, 1);
    if (!last) STAGE_B(1, 0, t3g);
    BAR; LGKM0; PRIO1; MMA(0, 1); PRIO0; BAR;
    DS_A(1, 1);
    if (!last) STAGE_B(1, 1, t3g);
    BAR; LGKM0; PRIO1; MMA(1, 0); PRIO0; BAR;
    if (!last) STAGE_A(1, 0, t3g);
    BAR; PRIO1; MMA(1, 1); PRIO0;
    if (!last) VM6;
    BAR;
  }

  const int orow0 = ti * 256 + wr * 128 + ((lane >> 4) << 2);
  const int ocol0 = tj * 256 + wc * 64 + fr;
#pragma unroll
  for (int m = 0; m < 8; ++m) {
#pragma unroll
    for (int n = 0; n < 4; ++n) {
      const int col = ocol0 + n * 16;
      const float bv = bias ? bias[col] : 0.0f;
#pragma unroll
      for (int j = 0; j < 4; ++j) {
        const int row = orow0 + m * 16 + j;
        const float v = acc[m][n][j] * scale + bv;
        const size_t idx = (size_t)bz * (size_t)sC + (size_t)row * ldc + col;
        if (OUTF32) ((float*)Cv)[idx] = v;
        else        ((u16*)Cv)[idx]   = f2bf(v);
      }
    }
  }
#undef GLL
#undef STAGE_A
#undef STAGE_B
#undef DS_A
#undef DS_B
#undef MMA
#undef BAR
#undef LGKM0
#undef VM6
#undef VM0
#undef PRIO1
#undef PRIO0
}

// ---------------- BMx256 8-phase body (Gt/Uw/Wt/QK/PV paths) ----------------
// EPI 0: bf16 out (+col-bias +row-bias). EPI 1: QK — E=exp(clamp((acc+ru+rv)
// *scale)-5), mask cl<rl+dco, bf16 store + row partial sums -> sumP.
// EPI 2: PV — f32 = acc*inv + col-bias; inv from sumP partials in-kernel.
template <int BM, int EPI, int LDA, int LDB, int LDC, int KK, int K0CT>
__device__ __forceinline__ void gemm_body(
    const u16* __restrict__ Ab, const u16* __restrict__ Bb,
    void* __restrict__ Cp, const float* __restrict__ bias,
    const float* __restrict__ rbias, int rk0, float scale, size_t cbase,
    int ti, int tj, u16* __restrict__ AsP, u16* __restrict__ BsP,
    float* __restrict__ sumP, int dco,
    const float* __restrict__ ruP, const float* __restrict__ rvP) {
  constexpr int WM = BM / 2;
  constexpr int MH = BM / 64;
  constexpr int FM = 2 * MH;
  constexpr int HR = BM / 4;
  constexpr int LA = BM / 128;

  const int k0 = (K0CT >= 0) ? K0CT : rk0;

  const int tid = threadIdx.x;
  const int wave = tid >> 6, lane = tid & 63;
  const int wr = wave >> 2, wc = wave & 3;
  const int fr = lane & 15;
  const int kb16 = (lane >> 4) * 16;
  const int swz = (fr & 7) << 4;
  const int cs0 = kb16 ^ swz;
  const int cs1 = (64 + kb16) ^ swz;
  const int aRowOff = (wr * WM + fr) * 128;
  const int bRowOff = (wc * 64 + fr) * 128;

  __shared__ float invLds[(EPI == 2) ? BM : 1];
  if constexpr (EPI == 2) {
    if (tid < BM) {
      int s = ti * BM + tid;
      float a = 0.f;
      for (int q2 = s >> 8; q2 < 8; ++q2) a += sumP[q2 * 2048 + s];
      invLds[tid] = 1.0f / a;
    }
  }

  size_t gAo[2][LA], gBo[2][2];
  u32 ldsA[2][LA], ldsB[2][2];
#pragma unroll
  for (int h = 0; h < 2; ++h) {
#pragma unroll
    for (int l = 0; l < LA; ++l) {
      int i = l * 512 + tid;
      int rih = i >> 3, ch8 = i & 7;
      int rA = (rih % HR) + (rih / HR) * WM + h * HR;
      int cbA = (ch8 << 4) ^ ((rA & 7) << 4);
      gAo[h][l] = (size_t)rA * LDA + (cbA >> 1);
      ldsA[h][l] = (u32)(rA * 8 + ch8) * 16;
    }
#pragma unroll
    for (int l = 0; l < 2; ++l) {
      int i = l * 512 + tid;
      int rih = i >> 3, ch8 = i & 7;
      int rB = (rih & 31) + ((rih >> 5) << 6) + h * 32;
      int cbB = (ch8 << 4) ^ ((rB & 7) << 4);
      gBo[h][l] = (size_t)rB * LDB + (cbB >> 1);
      ldsB[h][l] = (u32)(rB * 8 + ch8) * 16;
    }
  }
  const size_t aBase = (size_t)(ti * BM) * LDA;
  const size_t bBase = (size_t)(tj * 256) * LDB;
  const int niter = (KK - k0) / 128;

  f32x4 acc[FM][4] = {};
  bf16x8 aF[MH][2], bF[4][2];

#define GLL(gaddr, laddr)                                        \
  __builtin_amdgcn_global_load_lds(                              \
      (const __attribute__((address_space(1))) void*)(gaddr),    \
      (__attribute__((address_space(3))) void*)(laddr), 16, 0, 0)

#define STAGE_A(buf, h, t)                                                   \
  do {                                                                       \
    const size_t _kt = aBase + (size_t)(k0 + (t) * 64);                      \
    _Pragma("unroll") for (int _l = 0; _l < LA; ++_l)                        \
        GLL(Ab + _kt + gAo[h][_l],                                           \
            (char*)(AsP + (buf) * (BM * 64)) + ldsA[h][_l]);                 \
  } while (0)
#define STAGE_B(buf, h, t)                                                   \
  do {                                                                       \
    const size_t _kt = bBase + (size_t)(k0 + (t) * 64);                      \
    _Pragma("unroll") for (int _l = 0; _l < 2; ++_l)                         \
        GLL(Bb + _kt + gBo[h][_l],                                           \
            (char*)(BsP + (buf) * (256 * 64)) + ldsB[h][_l]);                \
  } while (0)

#define DS_A(buf, qm)                                                        \
  do {                                                                       \
    const char* _pa =                                                        \
        (const char*)(AsP + (buf) * (BM * 64)) + aRowOff + (qm) * (MH * 2048); \
    _Pragma("unroll") for (int mm = 0; mm < MH; ++mm) {                      \
      aF[mm][0] = *(const bf16x8*)(_pa + mm * 2048 + cs0);                   \
      aF[mm][1] = *(const bf16x8*)(_pa + mm * 2048 + cs1);                   \
    }                                                                        \
  } while (0)
#define DS_B(buf, nh)                                                        \
  do {                                                                       \
    const char* _pb = (const char*)(BsP + (buf) * (256 * 64)) + bRowOff;     \
    _Pragma("unroll") for (int nn = 0; nn < 2; ++nn) {                       \
      bF[(nh)*2 + nn][0] = *(const bf16x8*)(_pb + ((nh)*2 + nn) * 2048 + cs0); \
      bF[(nh)*2 + nn][1] = *(const bf16x8*)(_pb + ((nh)*2 + nn) * 2048 + cs1); \
    }                                                                        \
  } while (0)

#define MMA(qm, nh)                                                          \
  do {                                                                       \
    _Pragma("unroll") for (int mm = 0; mm < MH; ++mm)                        \
    _Pragma("unroll") for (int nn = 0; nn < 2; ++nn) {                       \
      f32x4 _c = acc[(qm)*MH + mm][(nh)*2 + nn];                             \
      _c = __builtin_amdgcn_mfma_f32_16x16x32_bf16(aF[mm][0], bF[(nh)*2+nn][0], _c, 0, 0, 0); \
      _c = __builtin_amdgcn_mfma_f32_16x16x32_bf16(aF[mm][1], bF[(nh)*2+nn][1], _c, 0, 0, 0); \
      acc[(qm)*MH + mm][(nh)*2 + nn] = _c;                                   \
    }                                                                        \
  } while (0)

#define BAR __builtin_amdgcn_s_barrier()
#define LGKM0 asm volatile("s_waitcnt lgkmcnt(0)" ::: "memory")
#define VMN                                                                  \
  do {                                                                       \
    if constexpr (BM == 256)                                                 \
      asm volatile("s_waitcnt vmcnt(6)" ::: "memory");                       \
    else                                                                     \
      asm volatile("s_waitcnt vmcnt(5)" ::: "memory");                       \
  } while (0)
#define VM0 asm volatile("s_waitcnt vmcnt(0)" ::: "memory")
#define PRIO1 __builtin_amdgcn_s_setprio(1)
#define PRIO0 __builtin_amdgcn_s_setprio(0)

  STAGE_B(0, 0, 0); STAGE_B(0, 1, 0); STAGE_A(0, 0, 0); STAGE_A(0, 1, 0);
  STAGE_B(1, 0, 1); STAGE_B(1, 1, 1); STAGE_A(1, 0, 1);
  VMN; BAR;

#pragma unroll 1
  for (int it = 0; it < niter; ++it) {
    const bool last = (it == niter - 1);
    const int t1g = 2 * it + 1, t2g = 2 * it + 2, t3g = 2 * it + 3;

    DS_A(0, 0); DS_B(0, 0);
    STAGE_A(1, 1, t1g);
    BAR; LGKM0; PRIO1; MMA(0, 0); PRIO0; BAR;
    DS_B(0, 1);
    if (!last) STAGE_B(0, 0, t2g);
    BAR; LGKM0; PRIO1; MMA(0, 1); PRIO0; BAR;
    DS_A(0, 1);
    if (!last) STAGE_B(0, 1, t2g);
    BAR; LGKM0; PRIO1; MMA(1, 0); PRIO0; BAR;
    if (!last) STAGE_A(0, 0, t2g);
    BAR; PRIO1; MMA(1, 1); PRIO0;
    if (last) { VM0; } else { VMN; }
    BAR;
    DS_A(1, 0); DS_B(1, 0);
    if (!last) STAGE_A(0, 1, t2g);
    BAR; LGKM0; PRIO1; MMA(0, 0); PRIO0; BAR;
    DS_B(1, 1);
    if (!last) STAGE_B(1, 0, t3g);
    BAR; LGKM0; PRIO1; MMA(0, 1); PRIO0; BAR;
    DS_A(1, 1);
    if (!last) STAGE_B(1, 1, t3g);
    BAR; LGKM0; PRIO1; MMA(1, 0); PRIO0; BAR;
    if (!last) STAGE_A(1, 0, t3g);
    BAR; PRIO1; MMA(1, 1); PRIO0;
    if (!last) VMN;
    BAR;
  }

  const int orowL = wr * WM + ((lane >> 4) << 2);
  const int orow0 = ti * BM + orowL;
  const int ocol0 = tj * 256 + wc * 64 + fr;

  if constexpr (EPI == 1) {
    float* slds = (float*)AsP;  // [BM][4] cross-wave reduce buffer
#pragma unroll
    for (int m = 0; m < FM; ++m) {
#pragma unroll
      for (int j = 0; j < 4; ++j) {
        const int rl = orowL + m * 16 + j;
        const int row = ti * BM + rl;
        const float ru = ruP[row];
        float rsum = 0.f;
#pragma unroll
        for (int n = 0; n < 4; ++n) {
          const int cl = wc * 64 + fr + n * 16;
          const int col = tj * 256 + cl;
          float v = (acc[m][n][j] + ru + rvP[col]) * scale;
          v = fminf(fmaxf(v, -1.0e9f), 1.0e9f);  // CLAMP
          v = fminf(v, 60.0f);                   // overflow guard
          float e = __expf(v - 5.0f);
          if (cl < rl + dco) e = 0.f;            // causal-complement mask
          rsum += e;
          ((u16*)Cp)[cbase + (size_t)row * LDC + col] = f2bf(e);
        }
        rsum += __shfl_xor(rsum, 1, 64);
        rsum += __shfl_xor(rsum, 2, 64);
        rsum += __shfl_xor(rsum, 4, 64);
        rsum += __shfl_xor(rsum, 8, 64);
        if (fr == 0) slds[rl * 4 + wc] = rsum;
      }
    }
    __syncthreads();
    if (tid < BM) {
      float t = slds[tid * 4 + 0] + slds[tid * 4 + 1] +
                slds[tid * 4 + 2] + slds[tid * 4 + 3];
      sumP[ti * BM + tid] = t;
    }
  } else {
#pragma unroll
    for (int m = 0; m < FM; ++m) {
#pragma unroll
      for (int j = 0; j < 4; ++j) {
        const int row = orow0 + m * 16 + j;
        float mul = (EPI == 2) ? invLds[orowL + m * 16 + j] : 1.0f;
        float rb = (EPI == 0 && rbias) ? rbias[row] : 0.0f;
#pragma unroll
        for (int n = 0; n < 4; ++n) {
          const int col = ocol0 + n * 16;
          const float bv = bias ? bias[col] : 0.0f;
          const size_t idx = cbase + (size_t)row * LDC + col;
          if constexpr (EPI == 2) {
            ((float*)Cp)[idx] = acc[m][n][j] * mul + bv;
          } else {
            ((u16*)Cp)[idx] = f2bf(acc[m][n][j] + bv + rb);
          }
        }
      }
    }
  }
#undef GLL
#undef STAGE_A
#undef STAGE_B
#undef DS_A
#undef DS_B
#undef MMA
#undef BAR
#undef LGKM0
#undef VMN
#undef VM0
#undef PRIO1
#undef PRIO0
}

// ---- prep2 (512-thr): Gt (32 blk) | Uw (32 blk) ----------------------------
__global__ __launch_bounds__(512, 2) void prep2(
    const u16* __restrict__ wqb, const u16* __restrict__ wkb,
    const u16* __restrict__ wvb, const u16* __restrict__ w0t,
    u16* __restrict__ Gt, u16* __restrict__ Uw) {
  __shared__ u16 As[2][128 * 64];
  __shared__ u16 Bs[2][256 * 64];
  int b = blockIdx.x;
  if (b < 32) {
    // Gt[c][d] = sum_e wk[c][e] wq[d][e]
    int ti = b & 7, tj = b >> 3;
    gemm_body<128, 0, 1024, 1024, 1024, 1024, 0>(
        wkb, wqb, Gt, nullptr, nullptr, 0, 1.0f, 0, ti, tj,
        &As[0][0], &Bs[0][0], nullptr, 0, nullptr, nullptr);
  } else {
    // Uw[e][c] = sum_d w0t[e][d] wv[c][d]
    int b2 = b - 32;
    int ti = b2 & 7, tj = b2 >> 3;
    gemm_body<128, 0, 1024, 1024, 1024, 1024, 0>(
        w0t, wvb, Uw, nullptr, nullptr, 0, 1.0f, 0, ti, tj,
        &As[0][0], &Bs[0][0], nullptr, 0, nullptr, nullptr);
  }
}

// ---- combined QK^T (BM=256, first, LPT) + Wt (BM=128, filler) --------------
// QK: scores E from xnG.xn^T, triangular (tj>=tq), batch->XCD affinity.
// Wt: Wt[bz][e][t] = sum_c Uw[e][c] xn[bz][t][c] + wb[e]; bz->XCD affinity.
__global__ __launch_bounds__(512, 2) void gemm_qkwt(
    const u16* __restrict__ xnG, const u16* __restrict__ xn,
    const u16* __restrict__ Uw, u16* __restrict__ Wt, u16* __restrict__ sc,
    float* __restrict__ sumP, const float* __restrict__ ru,
    const float* __restrict__ rv, const float* __restrict__ wb,
    int qkBlocks, int b0, int nb, float qk_scale) {
  __shared__ u16 As[2][256 * 64];
  __shared__ u16 Bs[2][256 * 64];
  const long long sXN = 2048LL * 1024, sWt = 1024LL * 2048, sS = 2048LL * 2048;
  int x = blockIdx.x;
  if (x < qkBlocks) {
    int bzl = x % nb, t36 = x / nb;
    int bz = b0 + bzl;
    int tq = 0, rem = t36;
    for (;;) { int L = 8 - tq; if (rem < L) break; rem -= L; ++tq; }
    int tj = tq + rem;
    gemm_body<256, 1, 1024, 1024, 2048, 1024, 0>(
        xnG + (size_t)bz * sXN, xn + (size_t)bz * sXN, sc, nullptr, nullptr,
        0, qk_scale, (size_t)bzl * sS, tq, tj, &As[0][0], &Bs[0][0],
        sumP + ((size_t)bz * 8 + tj) * 2048, (tq - tj) * 256,
        ru + (size_t)bz * 2048, rv + (size_t)bz * 2048);
  } else {
    int x2 = x - qkBlocks;           // 0..511
    int bz = x2 & 7;                 // XCD affinity
    int o = x2 >> 3;                 // 0..63
    int ti = o & 7, tj = o >> 3;     // ti-fastest
    gemm_body<128, 0, 1024, 1024, 2048, 1024, 0>(
        Uw, xn + (size_t)bz * sXN, Wt, nullptr, wb, 0, 1.0f,
        (size_t)bz * sWt, ti, tj, &As[0][0], &Bs[0][0],
        nullptr, 0, nullptr, nullptr);
  }
}

// ---- PV dispatch (BM=128), batch->XCD + LPT; inv folded --------------------
__global__ __launch_bounds__(512, 2) void gemm_pv(
    const u16* __restrict__ sc, const u16* __restrict__ Wt,
    float* __restrict__ out, const float* __restrict__ b0v,
    float* __restrict__ sumP, int nb, int bA) {
  __shared__ u16 As[2][128 * 64];
  __shared__ u16 Bs[2][256 * 64];
  int x = blockIdx.x;
  int bzl = x % nb;
  int rem = x / nb;
  int ti = rem >> 2, tj = rem & 3;
  int bz = bA + bzl;
  gemm_body<128, 2, 2048, 2048, 1024, 2048, -1>(
      sc + (size_t)bzl * 2048 * 2048, Wt + (size_t)bz * 1024 * 2048, out, b0v,
      nullptr, ti * 128, 1.0f, (size_t)bz * 2048 * 1024, ti, tj,
      &As[0][0], &Bs[0][0], sumP + (size_t)bz * 8 * 2048, 0,
      nullptr, nullptr);
}

extern "C" void kernel_launch(void* const* d_in, const int* in_sizes, int n_in,
                              void* d_out, int out_size, void* d_ws, size_t ws_size,
                              hipStream_t stream) {
  (void)in_sizes; (void)n_in; (void)out_size;
  const float* x   = (const float*)d_in[0];
  const float* lnw = (const float*)d_in[1];
  const float* lnb = (const float*)d_in[2];
  const float* wq  = (const float*)d_in[3];
  const float* bq  = (const float*)d_in[4];
  const float* wk  = (const float*)d_in[5];
  const float* bk  = (const float*)d_in[6];
  const float* wv  = (const float*)d_in[7];
  const float* bv  = (const float*)d_in[8];
  const float* w0  = (const float*)d_in[9];
  const float* b0  = (const float*)d_in[10];
  float* out = (float*)d_out;

  const size_t ROWS = 16384;  // B*S
  char* ws = (char*)d_ws;
  size_t off = 0;
  auto alloc = [&](size_t bytes) -> void* {
    void* p = ws + off;
    off += (bytes + 255) & ~(size_t)255;
    return p;
  };
  u16*   xn   = (u16*)alloc(ROWS * 1024 * 2);            // 32 MB
  u16*   w0t  = (u16*)alloc((size_t)1024 * 1024 * 2);    // 2 MB
  u16*   wqb  = (u16*)alloc((size_t)1024 * 1024 * 2);
  u16*   wkb  = (u16*)alloc((size_t)1024 * 1024 * 2);
  u16*   wvb  = (u16*)alloc((size_t)1024 * 1024 * 2);
  u16*   Gt   = (u16*)alloc((size_t)1024 * 1024 * 2);
  u16*   Uw   = (u16*)alloc((size_t)1024 * 1024 * 2);
  float* uvec = (float*)alloc(1024 * 4);
  float* vvec = (float*)alloc(1024 * 4);
  float* wb   = (float*)alloc(1024 * 4);
  float* sb   = (float*)alloc(256);
  float* ru   = (float*)alloc(ROWS * 4);                 // 64 KB
  float* rv   = (float*)alloc(ROWS * 4);
  float* sumP = (float*)alloc((size_t)8 * 8 * 2048 * 4); // 512 KB
  u16*   xnG  = (u16*)alloc(ROWS * 1024 * 2);            // 32 MB
  u16*   Wt   = (u16*)alloc(ROWS * 1024 * 2);            // 32 MB [8][1024][2048]

  const size_t CHUNK1 = (size_t)2048 * 2048 * 2;  // 8 MB per batch (E bf16)
  size_t avail = (ws_size > off) ? ws_size - off : 0;
  int NBCH = (int)(avail / CHUNK1);
  if (NBCH > 8) NBCH = 8;
  if (NBCH < 1) NBCH = 1;
  u16* sc = (u16*)(ws + off);

  // D1: LN + w0 transpose + weight casts + u/v/wb/sb
  prep1<<<dim3(22017), dim3(256), 0, stream>>>(
      x, lnw, lnb, wq, wk, wv, w0, bq, bk, bv,
      xn, w0t, wqb, wkb, wvb, uvec, vvec, wb, sb);
  // D2: Gt, Uw (weight-space GEMMs, 64 blocks)
  prep2<<<dim3(64), dim3(512), 0, stream>>>(wqb, wkb, wvb, w0t, Gt, Uw);
  // D3: ru/rv row dots (8 rows/block)
  ruv_kernel<<<dim3(2048), dim3(512), 0, stream>>>(xn, uvec, vvec, sb, ru, rv);
  // D4: xnG = xn @ G  (verbatim fast kernel; 256 blocks = 1 round)
  gemm256<0, 0><<<dim3(4, 64, 1), dim3(512), 0, stream>>>(
      xn, Gt, xnG, nullptr, 1024, 1024, 1024, 1024, 1.0f, 0, 0, 0);

  float qk_scale = (float)(1.0 / (std::sqrt(1024.0) + 1e-9));

  for (int bA = 0; bA < 8; bA += NBCH) {
    int nb = 8 - bA;
    if (nb > NBCH) nb = NBCH;
    int qkB = nb * 36;
    int wtB = (bA == 0) ? 512 : 0;  // Wt (BM=128) for ALL batches, first pass
    gemm_qkwt<<<dim3(qkB + wtB), dim3(512), 0, stream>>>(
        xnG, xn, Uw, Wt, sc, sumP, ru, rv, wb, qkB, bA, nb, qk_scale);
    gemm_pv<<<dim3(64 * nb), dim3(512), 0, stream>>>(
        sc, Wt, out, b0, sumP, nb, bA);
  }
}